// Round 9
// baseline (496.609 us; speedup 1.0000x reference)
//
#include <hip/hip_runtime.h>

typedef _Float16 v8h __attribute__((ext_vector_type(8)));
typedef _Float16 v4h __attribute__((ext_vector_type(4)));
typedef float    v4f __attribute__((ext_vector_type(4)));

template<int V> struct IC { static constexpr int value = V; };

__device__ __forceinline__ float fast_tanh(float x) {
    float e = __expf(2.0f * x);
    return 1.0f - 2.0f / (e + 1.0f);
}

// ---------------------------------------------------------------------------
// pack layout (halves), UNCHANGED from validated rounds 2-8 (role-symmetric
// fragment: lane(l15,s) -> own=l15, k=s*8+j).
//  hidden: idx = ((((pipe*3+l)*8 + nt)*4 + kk)*64 + lane)*8 + j     [0, 98304)
//  L0:     98304 + ((pipe*8 + nt)*64 + lane)*8 + j                  [98304, 106496)
// ---------------------------------------------------------------------------
__global__ void pack_weights(const float* __restrict__ dpWh,
                             const float* __restrict__ icWh,
                             const float* __restrict__ dpWin,
                             const float* __restrict__ icWin,
                             _Float16* __restrict__ out) {
    int idx = blockIdx.x * 256 + threadIdx.x;
    if (idx < 98304) {
        int j    = idx & 7;
        int lane = (idx >> 3) & 63;
        int kk   = (idx >> 9) & 3;
        int nt   = (idx >> 11) & 7;
        int lp   = idx >> 14;           // 0..5
        int l    = lp % 3;
        const float* src = (lp >= 3) ? icWh : dpWh;
        int k = kk * 32 + (lane >> 4) * 8 + j;
        int n = nt * 16 + (lane & 15);
        out[idx] = (_Float16)src[(l * 128 + k) * 128 + n];
    } else if (idx < 106496) {
        int f    = idx - 98304;
        int j    = f & 7;
        int lane = (f >> 3) & 63;
        int nt   = (f >> 9) & 7;
        int pipe = (f >> 12) & 1;
        int k = (lane >> 4) * 8 + j;
        int n = nt * 16 + (lane & 15);
        float v = 0.0f;
        if (pipe == 0) { if (k < 4) v = dpWin[k * 128 + n]; }
        else           { if (k < 3) v = icWin[k * 128 + n]; }
        out[idx] = (_Float16)v;
    }
}

// LDS (dynamic, 71680 B -> 2 blocks/CU = 4 waves/SIMD):
//   half-batch act: 128 vrows (2 sets x {4 streams x 16 phys}) x ROWH halves.
//   [0,     34816)  act0
//   [34816, 69632)  act1
//   [69632, 70656)  woutb: f32[2][128]
//   [70656, 71680)  cbuf : f32[256]  (global vrow = set*64 + st*16 + phys)
#define ROWH 136
#define ABUFH (128 * ROWH)
#define SMEM_BYTES 71680

__launch_bounds__(512, 4)
__global__ void node_main(const float* __restrict__ tx,
                          const float* __restrict__ dpBin, const float* __restrict__ dpBh,
                          const float* __restrict__ dpWout, const float* __restrict__ dpBout,
                          const float* __restrict__ icBin, const float* __restrict__ icBh,
                          const float* __restrict__ icWout, const float* __restrict__ icBout,
                          const _Float16* __restrict__ pack,
                          float* __restrict__ outPot, float* __restrict__ outAcc,
                          int N)
{
    extern __shared__ char smem[];
    _Float16* act0 = (_Float16*)smem;
    _Float16* act1 = act0 + ABUFH;
    float* woutb = (float*)(smem + 69632);
    float* cbuf  = (float*)(smem + 70656);

    const int tid  = threadIdx.x;
    const int wave = tid >> 6;          // 0..7 = my 16-feature slice cs
    const int lane = tid & 63;
    const int l15  = lane & 15;
    const int s    = lane >> 4;
    const int cs   = wave;

    if (tid < 128) {
        woutb[tid]       = dpWout[tid];
        woutb[128 + tid] = icWout[tid];
    }

    // ---- persistent weights: my cs-slice of all 6 hidden layers (A-operand) ----
    v8h wreg[6][4];
    #pragma unroll
    for (int L = 0; L < 6; L++)
        #pragma unroll
        for (int kk = 0; kk < 4; kk++)
            wreg[L][kk] = *(const v8h*)(pack + (((L * 8 + cs) * 4 + kk) << 9) + (lane << 3));

    // per-thread bias vectors for my 4 output features (rows s*4..s*4+3)
    const int fb = cs * 16 + s * 4;
    v4f bias4[8];   // [0]=dp Bin, [1..3]=dp Bh, [4]=ic Bin, [5..7]=ic Bh
    #pragma unroll
    for (int j = 0; j < 4; j++) {
        bias4[0][j] = dpBin[fb + j];
        bias4[4][j] = icBin[fb + j];
    }
    #pragma unroll
    for (int l = 0; l < 3; l++)
        #pragma unroll
        for (int j = 0; j < 4; j++) {
            bias4[1 + l][j] = dpBh[l * 128 + fb + j];
            bias4[5 + l][j] = icBh[l * 128 + fb + j];
        }
    const float boutd = dpBout[0];
    const float bouti = icBout[0];

    // unit-tangent B-fragments (constants: e_k at k = 0..3)
    v8h efr[4];
    {
        v8h e0 = {}, e1 = {}, e2 = {}, e3 = {};
        if (s == 0) {
            e0[0] = (_Float16)1.0f; e1[1] = (_Float16)1.0f;
            e2[2] = (_Float16)1.0f; e3[3] = (_Float16)1.0f;
        }
        efr[0] = e0; efr[1] = e1; efr[2] = e2; efr[3] = e3;
    }
    __syncthreads();

    // ---- static LDS bases ----
    _Float16* ep0 = act0 + l15 * ROWH + cs * 16 + s * 4;   // epilogue writes
    _Float16* ep1 = act1 + l15 * ROWH + cs * 16 + s * 4;
    const _Float16* rd0 = act0 + l15 * ROWH + s * 8;       // B-fragment reads
    const _Float16* rd1 = act1 + l15 * ROWH + s * 8;

    // epilogue: lane holds 4 consecutive features of ONE virtual row
    auto epi_p = [&](v4f acc, v4f& Dk, _Float16* p) {     // primal tile
        float h0 = fast_tanh(acc[0]), h1 = fast_tanh(acc[1]);
        float h2 = fast_tanh(acc[2]), h3 = fast_tanh(acc[3]);
        Dk[0] = 1.0f - h0 * h0; Dk[1] = 1.0f - h1 * h1;
        Dk[2] = 1.0f - h2 * h2; Dk[3] = 1.0f - h3 * h3;
        v4h w = {(_Float16)h0, (_Float16)h1, (_Float16)h2, (_Float16)h3};
        *(v4h*)p = w;
    };
    auto epi_t = [&](v4f acc, const v4f& Dk, _Float16* p) { // tangent tile
        v4h w = {(_Float16)(Dk[0] * acc[0]), (_Float16)(Dk[1] * acc[1]),
                 (_Float16)(Dk[2] * acc[2]), (_Float16)(Dk[3] * acc[3])};
        *(v4h*)p = w;
    };

    // one hidden layer over a half-batch: 8 stream-uniform tiles (2 local sets)
    // ic1c: true iff local set 1 is the ic pipe (i.e. half g==1)
    auto hpass = [&](auto Lc, auto G1c, const _Float16* rb, _Float16* wb) {
        constexpr int  L   = decltype(Lc)::value;
        constexpr bool IC1 = (decltype(G1c)::value == 1);
        #pragma unroll
        for (int ls = 0; ls < 2; ls++) {
            const bool icp = IC1 && (ls == 1);
            const v8h* W = icp ? wreg[L + 3] : wreg[L];
            v4f Dk;
            #pragma unroll
            for (int st = 0; st < 4; st++) {
                const int ro = (ls * 64 + st * 16) * ROWH;
                v8h b0 = *(const v8h*)(rb + ro);
                v8h b1 = *(const v8h*)(rb + ro + 32);
                v8h b2 = *(const v8h*)(rb + ro + 64);
                v8h b3 = *(const v8h*)(rb + ro + 96);
                v4f acc;
                if (st == 0) acc = icp ? bias4[5 + L] : bias4[1 + L];
                else { v4f z = {0.f, 0.f, 0.f, 0.f}; acc = z; }
                acc = __builtin_amdgcn_mfma_f32_16x16x32_f16(W[0], b0, acc, 0, 0, 0);
                acc = __builtin_amdgcn_mfma_f32_16x16x32_f16(W[1], b1, acc, 0, 0, 0);
                acc = __builtin_amdgcn_mfma_f32_16x16x32_f16(W[2], b2, acc, 0, 0, 0);
                acc = __builtin_amdgcn_mfma_f32_16x16x32_f16(W[3], b3, acc, 0, 0, 0);
                _Float16* p = wb + (ls * 64 + st * 16) * ROWH;
                if (st == 0) epi_p(acc, Dk, p);
                else         epi_t(acc, Dk, p);
            }
        }
    };

    const float NP0 = 1.0f - 0.7745966692414834f;   // GL node+1
    const float NP2 = 1.0f + 0.7745966692414834f;

    const int nbat = (N + 15) >> 4;
    for (int b = blockIdx.x; b < nbat; b += gridDim.x) {
        // ---- L0 weights (L2/L1-resident after first batch) ----
        v8h wl0d = *(const v8h*)(pack + 98304 + ((cs * 64 + lane) << 3));
        v8h wl0i = *(const v8h*)(pack + 98304 + (((8 + cs) * 64 + lane) << 3));

        // ---- geometry for phys row l15 (per-lane; no shuffles needed) ----
        int prow = b * 16 + l15;
        float4 q = (prow < N) ? ((const float4*)tx)[prow] : make_float4(0.f, 1.f, 1.f, 1.f);
        float t = q.x, x = q.y, y = q.z, z = q.w;
        float r2 = x * x + y * y + z * z;
        float r  = sqrtf(r2 + 1e-12f);
        float rinv = 1.0f / r;
        float uc = fminf(1.0f, fmaxf(-1.0f, z * rinv));
        float th = acosf(uc);
        float ph = atan2f(y, x);
        float rinv3 = rinv * rinv * rinv;
        float dacos = -1.0f / sqrtf(fmaxf(1.0f - uc * uc, 1e-30f));
        float dthx = dacos * (-x * z * rinv3);
        float dthy = dacos * (-y * z * rinv3);
        float dthz = dacos * (rinv - z * z * rinv3);
        float rho2 = fmaxf(x * x + y * y, 1e-30f);
        float dphx = -y / rho2;
        float dphy =  x / rho2;
        float opr  = 1.0f + r;
        float sEnv = -1.0f / opr;
        float dsdr =  1.0f / (opr * opr);
        float den  = r * r + 0.1f;
        float isq  = 1.0f / sqrtf(den);
        float Aan  = -isq;
        float dAdr = r * isq * isq * isq;
        float xr = x * rinv, yr = y * rinv, zr = z * rinv;

        // primal B-frags for all 4 global sets (s==0 lanes carry data)
        v8h prim[4];
        {
            v8h z4 = {};
            #pragma unroll
            for (int set = 0; set < 3; set++) {
                float np1 = (set == 0) ? NP0 : ((set == 1) ? 1.0f : NP2);
                float ts = 0.5f * t * np1;
                v8h pm = {};
                pm[0] = (_Float16)ts; pm[1] = (_Float16)r;
                pm[2] = (_Float16)th; pm[3] = (_Float16)ph;
                prim[set] = (s == 0) ? pm : z4;
            }
            v8h pi = {};
            pi[0] = (_Float16)r; pi[1] = (_Float16)th; pi[2] = (_Float16)ph;
            prim[3] = (s == 0) ? pi : z4;
        }

        // ---- two half-batches: global sets {0,1} then {2,3} ----
        #pragma unroll
        for (int g = 0; g < 2; g++) {
            // L0: 8 tiles (2 local sets x 4 streams) -> act0
            #pragma unroll
            for (int ls = 0; ls < 2; ls++) {
                const int set = g * 2 + ls;
                const bool icp = (set == 3);
                v8h wf = icp ? wl0i : wl0d;
                v4f Dk;
                #pragma unroll
                for (int st = 0; st < 4; st++) {
                    v8h bf;
                    if (st == 0) bf = prim[set];
                    else         bf = efr[icp ? (st - 1) : st];
                    v4f acc;
                    if (st == 0) acc = icp ? bias4[4] : bias4[0];
                    else { v4f zz = {0.f, 0.f, 0.f, 0.f}; acc = zz; }
                    acc = __builtin_amdgcn_mfma_f32_16x16x32_f16(wf, bf, acc, 0, 0, 0);
                    _Float16* p = ep0 + (ls * 64 + st * 16) * ROWH;
                    if (st == 0) epi_p(acc, Dk, p);
                    else         epi_t(acc, Dk, p);
                }
            }
            __syncthreads();                           // act0 ready

            if (g == 0) {
                hpass(IC<0>{}, IC<0>{}, rd0, ep1); __syncthreads();
                hpass(IC<1>{}, IC<0>{}, rd1, ep0); __syncthreads();
                hpass(IC<2>{}, IC<0>{}, rd0, ep1); __syncthreads();
            } else {
                hpass(IC<0>{}, IC<1>{}, rd0, ep1); __syncthreads();
                hpass(IC<1>{}, IC<1>{}, rd1, ep0); __syncthreads();
                hpass(IC<2>{}, IC<1>{}, rd0, ep1); __syncthreads();
            }

            // out-dot via MFMA: my tile = `wave` (16 local vrows)
            {
                const bool icout = (g == 1) && (wave >= 4);
                const float* wsrc = woutb + (icout ? 128 : 0);
                v8h wof[4];
                #pragma unroll
                for (int kk = 0; kk < 4; kk++) {
                    v8h w = {};
                    if (l15 == 0)
                        #pragma unroll
                        for (int j = 0; j < 8; j++)
                            w[j] = (_Float16)wsrc[kk * 32 + s * 8 + j];
                    wof[kk] = w;
                }
                const _Float16* rp = act1 + (wave * 16 + l15) * ROWH + s * 8;
                v4f acc = {0.f, 0.f, 0.f, 0.f};
                acc = __builtin_amdgcn_mfma_f32_16x16x32_f16(wof[0], *(const v8h*)(rp),      acc, 0, 0, 0);
                acc = __builtin_amdgcn_mfma_f32_16x16x32_f16(wof[1], *(const v8h*)(rp + 32), acc, 0, 0, 0);
                acc = __builtin_amdgcn_mfma_f32_16x16x32_f16(wof[2], *(const v8h*)(rp + 64), acc, 0, 0, 0);
                acc = __builtin_amdgcn_mfma_f32_16x16x32_f16(wof[3], *(const v8h*)(rp + 96), acc, 0, 0, 0);
                if (s == 0) cbuf[g * 128 + wave * 16 + l15] = acc[0];
            }
            // next L0 writes act0 (free), h1 writes act1 only after next barrier
        }
        __syncthreads();                               // cbuf complete

        // ---- quadrature + envelope + chain rule (wave 0, lanes 0-15) ----
        if (wave == 0 && lane < 16) {
            int row = b * 16 + lane;
            if (row < N) {
                float ah = 0.5f * t;
                float vic = cbuf[192 + lane];
                float g1  = cbuf[208 + lane];
                float g2  = cbuf[224 + lane];
                float g3  = cbuf[240 + lane];
                float dsum = 0.f, ds1 = 0.f, ds2 = 0.f, ds3 = 0.f;
                const float wq[3] = {0.5555555555555556f, 0.8888888888888889f, 0.5555555555555556f};
                #pragma unroll
                for (int qq = 0; qq < 3; qq++) {
                    float w = wq[qq];
                    dsum += w * cbuf[qq * 64 + lane];
                    ds1  += w * cbuf[qq * 64 + 16 + lane];
                    ds2  += w * cbuf[qq * 64 + 32 + lane];
                    ds3  += w * cbuf[qq * 64 + 48 + lane];
                }
                float tcv  = (vic + bouti) + ah * (dsum + 2.0f * boutd);
                float dtcr = g1 + ah * ds1;
                float dtct = g2 + ah * ds2;
                float dtcp = g3 + ah * ds3;
                float pot = tcv * sEnv + Aan;
                float gx0 = sEnv * dtcr + tcv * dsdr + dAdr;
                float gx1 = sEnv * dtct;
                float gx2 = sEnv * dtcp;
                float ax = -(gx0 * xr + gx1 * dthx + gx2 * dphx);
                float ay = -(gx0 * yr + gx1 * dthy + gx2 * dphy);
                float az = -(gx0 * zr + gx1 * dthz);
                outPot[row] = pot;
                outAcc[row * 3 + 0] = ax;
                outAcc[row * 3 + 1] = ay;
                outAcc[row * 3 + 2] = az;
            }
        }
    }
}

extern "C" void kernel_launch(void* const* d_in, const int* in_sizes, int n_in,
                              void* d_out, int out_size, void* d_ws, size_t ws_size,
                              hipStream_t stream) {
    (void)n_in; (void)out_size;
    const float* tx     = (const float*)d_in[0];
    const float* dpWin  = (const float*)d_in[1];
    const float* dpBin  = (const float*)d_in[2];
    const float* dpWh   = (const float*)d_in[3];
    const float* dpBh   = (const float*)d_in[4];
    const float* dpWout = (const float*)d_in[5];
    const float* dpBout = (const float*)d_in[6];
    const float* icWin  = (const float*)d_in[7];
    const float* icBin  = (const float*)d_in[8];
    const float* icWh   = (const float*)d_in[9];
    const float* icBh   = (const float*)d_in[10];
    const float* icWout = (const float*)d_in[11];
    const float* icBout = (const float*)d_in[12];

    int N = in_sizes[0] / 4;
    if (ws_size < (size_t)(106496 * sizeof(_Float16))) return;
    _Float16* pack = (_Float16*)d_ws;
    float* outPot = (float*)d_out;
    float* outAcc = outPot + N;

    pack_weights<<<(106496 + 255) / 256, 256, 0, stream>>>(dpWh, icWh, dpWin, icWin, pack);

    (void)hipFuncSetAttribute(reinterpret_cast<const void*>(node_main),
                              hipFuncAttributeMaxDynamicSharedMemorySize, SMEM_BYTES);
    node_main<<<512, 512, SMEM_BYTES, stream>>>(tx,
        dpBin, dpBh, dpWout, dpBout,
        icBin, icBh, icWout, icBout,
        pack, outPot, outAcc, N);
}

// Round 10
// 402.771 us; speedup vs baseline: 1.2330x; 1.2330x over previous
//
#include <hip/hip_runtime.h>

typedef _Float16 v8h __attribute__((ext_vector_type(8)));
typedef _Float16 v4h __attribute__((ext_vector_type(4)));
typedef float    v4f __attribute__((ext_vector_type(4)));

template<int V> struct IC { static constexpr int value = V; };

__device__ __forceinline__ float fast_tanh(float x) {
    float e = __expf(2.0f * x);
    return 1.0f - 2.0f / (e + 1.0f);
}

// ---------------------------------------------------------------------------
// pack layout (halves), UNCHANGED from validated rounds 2-9 (role-symmetric
// fragment: lane(l15,s) -> own=l15, k=s*8+j).
//  hidden: idx = ((((pipe*3+l)*8 + nt)*4 + kk)*64 + lane)*8 + j     [0, 98304)
//  L0:     98304 + ((pipe*8 + nt)*64 + lane)*8 + j                  [98304, 106496)
// ---------------------------------------------------------------------------
__global__ void pack_weights(const float* __restrict__ dpWh,
                             const float* __restrict__ icWh,
                             const float* __restrict__ dpWin,
                             const float* __restrict__ icWin,
                             _Float16* __restrict__ out) {
    int idx = blockIdx.x * 256 + threadIdx.x;
    if (idx < 98304) {
        int j    = idx & 7;
        int lane = (idx >> 3) & 63;
        int kk   = (idx >> 9) & 3;
        int nt   = (idx >> 11) & 7;
        int lp   = idx >> 14;           // 0..5
        int l    = lp % 3;
        const float* src = (lp >= 3) ? icWh : dpWh;
        int k = kk * 32 + (lane >> 4) * 8 + j;
        int n = nt * 16 + (lane & 15);
        out[idx] = (_Float16)src[(l * 128 + k) * 128 + n];
    } else if (idx < 106496) {
        int f    = idx - 98304;
        int j    = f & 7;
        int lane = (f >> 3) & 63;
        int nt   = (f >> 9) & 7;
        int pipe = (f >> 12) & 1;
        int k = (lane >> 4) * 8 + j;
        int n = nt * 16 + (lane & 15);
        float v = 0.0f;
        if (pipe == 0) { if (k < 4) v = dpWin[k * 128 + n]; }
        else           { if (k < 3) v = icWin[k * 128 + n]; }
        out[idx] = (_Float16)v;
    }
}

// LDS (dynamic, 71680 B -> 2 blocks/CU = 4 waves/SIMD at VGPR<=128):
//   half-batch act: 128 vrows (2 sets x {4 streams x 16 phys}) x ROWH halves.
//   [0,     34816)  act0
//   [34816, 69632)  act1
//   [69632, 70656)  woutb: f32[2][128]
//   [70656, 71680)  cbuf : f32[256]  (global vrow = set*64 + st*16 + phys)
#define ROWH 136
#define ABUFH (128 * ROWH)
#define SMEM_BYTES 71680

// NOTE: minWaves=2 deliberately. Asking for 4 makes hipcc squeeze arch VGPRs
// to 64 and spill (measured rounds 4/6/9: WRITE_SIZE 65-362 MB). At the
// natural ~124 VGPR the HW already fits 4 waves/SIMD; LDS allows 2 blocks/CU.
__launch_bounds__(512, 2)
__global__ void node_main(const float* __restrict__ tx,
                          const float* __restrict__ dpBin, const float* __restrict__ dpBh,
                          const float* __restrict__ dpWout, const float* __restrict__ dpBout,
                          const float* __restrict__ icBin, const float* __restrict__ icBh,
                          const float* __restrict__ icWout, const float* __restrict__ icBout,
                          const _Float16* __restrict__ pack,
                          float* __restrict__ outPot, float* __restrict__ outAcc,
                          int N)
{
    extern __shared__ char smem[];
    _Float16* act0 = (_Float16*)smem;
    _Float16* act1 = act0 + ABUFH;
    float* woutb = (float*)(smem + 69632);
    float* cbuf  = (float*)(smem + 70656);

    const int tid  = threadIdx.x;
    const int wave = tid >> 6;          // 0..7 = my 16-feature slice cs
    const int lane = tid & 63;
    const int l15  = lane & 15;
    const int s    = lane >> 4;
    const int cs   = wave;

    if (tid < 128) {
        woutb[tid]       = dpWout[tid];
        woutb[128 + tid] = icWout[tid];
    }

    // ---- persistent weights: my cs-slice of all 6 hidden layers (A-operand) ----
    v8h wreg[6][4];
    #pragma unroll
    for (int L = 0; L < 6; L++)
        #pragma unroll
        for (int kk = 0; kk < 4; kk++)
            wreg[L][kk] = *(const v8h*)(pack + (((L * 8 + cs) * 4 + kk) << 9) + (lane << 3));

    // per-thread bias vectors for my 4 output features (rows s*4..s*4+3)
    const int fb = cs * 16 + s * 4;
    v4f bias4[8];   // [0]=dp Bin, [1..3]=dp Bh, [4]=ic Bin, [5..7]=ic Bh
    #pragma unroll
    for (int j = 0; j < 4; j++) {
        bias4[0][j] = dpBin[fb + j];
        bias4[4][j] = icBin[fb + j];
    }
    #pragma unroll
    for (int l = 0; l < 3; l++)
        #pragma unroll
        for (int j = 0; j < 4; j++) {
            bias4[1 + l][j] = dpBh[l * 128 + fb + j];
            bias4[5 + l][j] = icBh[l * 128 + fb + j];
        }
    const float boutd = dpBout[0];
    const float bouti = icBout[0];

    // unit-tangent B-fragments (constants: e_k at k = 0..3)
    v8h efr[4];
    {
        v8h e0 = {}, e1 = {}, e2 = {}, e3 = {};
        if (s == 0) {
            e0[0] = (_Float16)1.0f; e1[1] = (_Float16)1.0f;
            e2[2] = (_Float16)1.0f; e3[3] = (_Float16)1.0f;
        }
        efr[0] = e0; efr[1] = e1; efr[2] = e2; efr[3] = e3;
    }
    __syncthreads();

    // ---- static LDS bases ----
    _Float16* ep0 = act0 + l15 * ROWH + cs * 16 + s * 4;   // epilogue writes
    _Float16* ep1 = act1 + l15 * ROWH + cs * 16 + s * 4;
    const _Float16* rd0 = act0 + l15 * ROWH + s * 8;       // B-fragment reads
    const _Float16* rd1 = act1 + l15 * ROWH + s * 8;

    // epilogue: lane holds 4 consecutive features of ONE virtual row
    auto epi_p = [&](v4f acc, v4f& Dk, _Float16* p) {     // primal tile
        float h0 = fast_tanh(acc[0]), h1 = fast_tanh(acc[1]);
        float h2 = fast_tanh(acc[2]), h3 = fast_tanh(acc[3]);
        Dk[0] = 1.0f - h0 * h0; Dk[1] = 1.0f - h1 * h1;
        Dk[2] = 1.0f - h2 * h2; Dk[3] = 1.0f - h3 * h3;
        v4h w = {(_Float16)h0, (_Float16)h1, (_Float16)h2, (_Float16)h3};
        *(v4h*)p = w;
    };
    auto epi_t = [&](v4f acc, const v4f& Dk, _Float16* p) { // tangent tile
        v4h w = {(_Float16)(Dk[0] * acc[0]), (_Float16)(Dk[1] * acc[1]),
                 (_Float16)(Dk[2] * acc[2]), (_Float16)(Dk[3] * acc[3])};
        *(v4h*)p = w;
    };

    // one hidden layer over a half-batch: 8 stream-uniform tiles (2 local sets)
    auto hpass = [&](auto Lc, auto G1c, const _Float16* rb, _Float16* wb) {
        constexpr int  L   = decltype(Lc)::value;
        constexpr bool IC1 = (decltype(G1c)::value == 1);
        #pragma unroll
        for (int ls = 0; ls < 2; ls++) {
            const bool icp = IC1 && (ls == 1);
            const v8h* W = icp ? wreg[L + 3] : wreg[L];
            v4f Dk;
            #pragma unroll
            for (int st = 0; st < 4; st++) {
                const int ro = (ls * 64 + st * 16) * ROWH;
                v8h b0 = *(const v8h*)(rb + ro);
                v8h b1 = *(const v8h*)(rb + ro + 32);
                v8h b2 = *(const v8h*)(rb + ro + 64);
                v8h b3 = *(const v8h*)(rb + ro + 96);
                v4f acc;
                if (st == 0) acc = icp ? bias4[5 + L] : bias4[1 + L];
                else { v4f z = {0.f, 0.f, 0.f, 0.f}; acc = z; }
                acc = __builtin_amdgcn_mfma_f32_16x16x32_f16(W[0], b0, acc, 0, 0, 0);
                acc = __builtin_amdgcn_mfma_f32_16x16x32_f16(W[1], b1, acc, 0, 0, 0);
                acc = __builtin_amdgcn_mfma_f32_16x16x32_f16(W[2], b2, acc, 0, 0, 0);
                acc = __builtin_amdgcn_mfma_f32_16x16x32_f16(W[3], b3, acc, 0, 0, 0);
                _Float16* p = wb + (ls * 64 + st * 16) * ROWH;
                if (st == 0) epi_p(acc, Dk, p);
                else         epi_t(acc, Dk, p);
            }
        }
    };

    const float NP0 = 1.0f - 0.7745966692414834f;   // GL node+1
    const float NP2 = 1.0f + 0.7745966692414834f;

    const int nbat = (N + 15) >> 4;
    for (int b = blockIdx.x; b < nbat; b += gridDim.x) {
        // ---- L0 weights (L2/L1-resident after first batch) ----
        v8h wl0d = *(const v8h*)(pack + 98304 + ((cs * 64 + lane) << 3));
        v8h wl0i = *(const v8h*)(pack + 98304 + (((8 + cs) * 64 + lane) << 3));

        // ---- geometry for phys row l15 (per-lane; no shuffles needed) ----
        int prow = b * 16 + l15;
        float4 q = (prow < N) ? ((const float4*)tx)[prow] : make_float4(0.f, 1.f, 1.f, 1.f);
        float t = q.x, x = q.y, y = q.z, z = q.w;
        float r2 = x * x + y * y + z * z;
        float r  = sqrtf(r2 + 1e-12f);
        float rinv = 1.0f / r;
        float uc = fminf(1.0f, fmaxf(-1.0f, z * rinv));
        float th = acosf(uc);
        float ph = atan2f(y, x);
        float rinv3 = rinv * rinv * rinv;
        float dacos = -1.0f / sqrtf(fmaxf(1.0f - uc * uc, 1e-30f));
        float dthx = dacos * (-x * z * rinv3);
        float dthy = dacos * (-y * z * rinv3);
        float dthz = dacos * (rinv - z * z * rinv3);
        float rho2 = fmaxf(x * x + y * y, 1e-30f);
        float dphx = -y / rho2;
        float dphy =  x / rho2;
        float opr  = 1.0f + r;
        float sEnv = -1.0f / opr;
        float dsdr =  1.0f / (opr * opr);
        float den  = r * r + 0.1f;
        float isq  = 1.0f / sqrtf(den);
        float Aan  = -isq;
        float dAdr = r * isq * isq * isq;
        float xr = x * rinv, yr = y * rinv, zr = z * rinv;

        // primal B-frags for all 4 global sets (s==0 lanes carry data)
        v8h prim[4];
        {
            v8h z4 = {};
            #pragma unroll
            for (int set = 0; set < 3; set++) {
                float np1 = (set == 0) ? NP0 : ((set == 1) ? 1.0f : NP2);
                float ts = 0.5f * t * np1;
                v8h pm = {};
                pm[0] = (_Float16)ts; pm[1] = (_Float16)r;
                pm[2] = (_Float16)th; pm[3] = (_Float16)ph;
                prim[set] = (s == 0) ? pm : z4;
            }
            v8h pi = {};
            pi[0] = (_Float16)r; pi[1] = (_Float16)th; pi[2] = (_Float16)ph;
            prim[3] = (s == 0) ? pi : z4;
        }

        // ---- two half-batches: global sets {0,1} then {2,3} ----
        #pragma unroll
        for (int g = 0; g < 2; g++) {
            // L0: 8 tiles (2 local sets x 4 streams) -> act0
            #pragma unroll
            for (int ls = 0; ls < 2; ls++) {
                const int set = g * 2 + ls;
                const bool icp = (set == 3);
                v8h wf = icp ? wl0i : wl0d;
                v4f Dk;
                #pragma unroll
                for (int st = 0; st < 4; st++) {
                    v8h bf;
                    if (st == 0) bf = prim[set];
                    else         bf = efr[icp ? (st - 1) : st];
                    v4f acc;
                    if (st == 0) acc = icp ? bias4[4] : bias4[0];
                    else { v4f zz = {0.f, 0.f, 0.f, 0.f}; acc = zz; }
                    acc = __builtin_amdgcn_mfma_f32_16x16x32_f16(wf, bf, acc, 0, 0, 0);
                    _Float16* p = ep0 + (ls * 64 + st * 16) * ROWH;
                    if (st == 0) epi_p(acc, Dk, p);
                    else         epi_t(acc, Dk, p);
                }
            }
            __syncthreads();                           // act0 ready

            if (g == 0) {
                hpass(IC<0>{}, IC<0>{}, rd0, ep1); __syncthreads();
                hpass(IC<1>{}, IC<0>{}, rd1, ep0); __syncthreads();
                hpass(IC<2>{}, IC<0>{}, rd0, ep1); __syncthreads();
            } else {
                hpass(IC<0>{}, IC<1>{}, rd0, ep1); __syncthreads();
                hpass(IC<1>{}, IC<1>{}, rd1, ep0); __syncthreads();
                hpass(IC<2>{}, IC<1>{}, rd0, ep1); __syncthreads();
            }

            // out-dot via MFMA: my tile = `wave` (16 local vrows)
            {
                const bool icout = (g == 1) && (wave >= 4);
                const float* wsrc = woutb + (icout ? 128 : 0);
                v8h wof[4];
                #pragma unroll
                for (int kk = 0; kk < 4; kk++) {
                    v8h w = {};
                    if (l15 == 0)
                        #pragma unroll
                        for (int j = 0; j < 8; j++)
                            w[j] = (_Float16)wsrc[kk * 32 + s * 8 + j];
                    wof[kk] = w;
                }
                const _Float16* rp = act1 + (wave * 16 + l15) * ROWH + s * 8;
                v4f acc = {0.f, 0.f, 0.f, 0.f};
                acc = __builtin_amdgcn_mfma_f32_16x16x32_f16(wof[0], *(const v8h*)(rp),      acc, 0, 0, 0);
                acc = __builtin_amdgcn_mfma_f32_16x16x32_f16(wof[1], *(const v8h*)(rp + 32), acc, 0, 0, 0);
                acc = __builtin_amdgcn_mfma_f32_16x16x32_f16(wof[2], *(const v8h*)(rp + 64), acc, 0, 0, 0);
                acc = __builtin_amdgcn_mfma_f32_16x16x32_f16(wof[3], *(const v8h*)(rp + 96), acc, 0, 0, 0);
                if (s == 0) cbuf[g * 128 + wave * 16 + l15] = acc[0];
            }
            // g=1's L0 writes act0 (free); act1 is rewritten only after next barrier
        }
        __syncthreads();                               // cbuf complete

        // ---- quadrature + envelope + chain rule (wave 0, lanes 0-15) ----
        if (wave == 0 && lane < 16) {
            int row = b * 16 + lane;
            if (row < N) {
                float ah = 0.5f * t;
                float vic = cbuf[192 + lane];
                float g1  = cbuf[208 + lane];
                float g2  = cbuf[224 + lane];
                float g3  = cbuf[240 + lane];
                float dsum = 0.f, ds1 = 0.f, ds2 = 0.f, ds3 = 0.f;
                const float wq[3] = {0.5555555555555556f, 0.8888888888888889f, 0.5555555555555556f};
                #pragma unroll
                for (int qq = 0; qq < 3; qq++) {
                    float w = wq[qq];
                    dsum += w * cbuf[qq * 64 + lane];
                    ds1  += w * cbuf[qq * 64 + 16 + lane];
                    ds2  += w * cbuf[qq * 64 + 32 + lane];
                    ds3  += w * cbuf[qq * 64 + 48 + lane];
                }
                float tcv  = (vic + bouti) + ah * (dsum + 2.0f * boutd);
                float dtcr = g1 + ah * ds1;
                float dtct = g2 + ah * ds2;
                float dtcp = g3 + ah * ds3;
                float pot = tcv * sEnv + Aan;
                float gx0 = sEnv * dtcr + tcv * dsdr + dAdr;
                float gx1 = sEnv * dtct;
                float gx2 = sEnv * dtcp;
                float ax = -(gx0 * xr + gx1 * dthx + gx2 * dphx);
                float ay = -(gx0 * yr + gx1 * dthy + gx2 * dphy);
                float az = -(gx0 * zr + gx1 * dthz);
                outPot[row] = pot;
                outAcc[row * 3 + 0] = ax;
                outAcc[row * 3 + 1] = ay;
                outAcc[row * 3 + 2] = az;
            }
        }
    }
}

extern "C" void kernel_launch(void* const* d_in, const int* in_sizes, int n_in,
                              void* d_out, int out_size, void* d_ws, size_t ws_size,
                              hipStream_t stream) {
    (void)n_in; (void)out_size;
    const float* tx     = (const float*)d_in[0];
    const float* dpWin  = (const float*)d_in[1];
    const float* dpBin  = (const float*)d_in[2];
    const float* dpWh   = (const float*)d_in[3];
    const float* dpBh   = (const float*)d_in[4];
    const float* dpWout = (const float*)d_in[5];
    const float* dpBout = (const float*)d_in[6];
    const float* icWin  = (const float*)d_in[7];
    const float* icBin  = (const float*)d_in[8];
    const float* icWh   = (const float*)d_in[9];
    const float* icBh   = (const float*)d_in[10];
    const float* icWout = (const float*)d_in[11];
    const float* icBout = (const float*)d_in[12];

    int N = in_sizes[0] / 4;
    if (ws_size < (size_t)(106496 * sizeof(_Float16))) return;
    _Float16* pack = (_Float16*)d_ws;
    float* outPot = (float*)d_out;
    float* outAcc = outPot + N;

    pack_weights<<<(106496 + 255) / 256, 256, 0, stream>>>(dpWh, icWh, dpWin, icWin, pack);

    (void)hipFuncSetAttribute(reinterpret_cast<const void*>(node_main),
                              hipFuncAttributeMaxDynamicSharedMemorySize, SMEM_BYTES);
    node_main<<<512, 512, SMEM_BYTES, stream>>>(tx,
        dpBin, dpBh, dpWout, dpBout,
        icBin, icBh, icWout, icBout,
        pack, outPot, outAcc, N);
}